// Round 7
// baseline (118.750 us; speedup 1.0000x reference)
//
#include <hip/hip_runtime.h>

// NonLinearConv2d: unfold(3x3,pad1) -> sum_k f((v_k - theta_kc)/D) with
// f(a) = softplus(a)^2 - softplus(a-DLT)^2, then BatchNorm2d (training,
// biased stats) per channel.
//
// Round 7: occupancy push. Rolling per-(ki,kj,ci) {load -> exp -> 4ch 2-log
// term} so no Ev[27] array is live (natural VGPR ~35); __launch_bounds__
// (256,8) pins <=64 VGPR -> 8 waves/SIMD (was ~4). Scalar r4 math (packing
// reverted). Two kernels; finish = r5's 512-block fused stats+apply.

constexpr float INV_D  = 13.333333333333334f;   // 1/(2*n*VT) = 1/0.075
constexpr float C_NEG  = 0.2635971381157267f;   // e^-(V_D/DENOM) = e^-4/3
// V = acc * OUT_SC;  OUT_SC = ALPHA * R_TIA * ln(2)^2
constexpr double OUT_SC = 5.625e-5 * 0.48045301391820142;
constexpr int   NCHUNK = 512;                   // 32768 pixels / 64

// ---------------------------------------------------------------------------
// Kernel 1: raw acc (into d_out) + per-(channel,chunk) partial sum / sumsq.
// Grid: 2048 = 512 pixel-chunks x 4 channel-groups; block 256 = 4 waves;
// wave handles 64 consecutive pixels x 4 channels.
// ---------------------------------------------------------------------------
__global__ __launch_bounds__(256, 8)
void nlc_compute(const float* __restrict__ x, const float* __restrict__ theta,
                 float* __restrict__ vout, float* __restrict__ psum,
                 float* __restrict__ psq)
{
    __shared__ alignas(16) float thc[27 * 16];  // e^{-theta*INV_D}, 16 ch
    const int tid   = threadIdx.x;
    const int chunk = blockIdx.x >> 2;
    const int cbase = (blockIdx.x & 3) * 16;

    for (int i = tid; i < 27 * 16; i += 256) {
        const int k = i >> 4, cc = i & 15;
        thc[i] = __expf(-theta[k * 64 + cbase + cc] * INV_D);
    }
    __syncthreads();

    const int lane = tid & 63;
    const int wv   = tid >> 6;
    const int p    = chunk * 64 + lane;   // global pixel id
    const int n    = p >> 10;
    const int hw   = p & 1023;
    const int h    = hw >> 5;
    const int w    = hw & 31;

    const float* xn = x + n * 3072;
    const float4* thv4 = reinterpret_cast<const float4*>(thc);

    float acc0 = 0.f, acc1 = 0.f, acc2 = 0.f, acc3 = 0.f;

    // rolling: per (ki,kj) compute mask/addr once; per ci: load (L1-hit),
    // exp, then the 4-channel 2-log term. No Ev array -> ~35 live VGPRs.
#pragma unroll
    for (int ki = 0; ki < 3; ++ki) {
        const int  hh = h + ki - 1;
#pragma unroll
        for (int kj = 0; kj < 3; ++kj) {
            const int  ww = w + kj - 1;
            const bool ok = ((unsigned)hh < 32u) & ((unsigned)ww < 32u);
            const int  ad = ok ? (hh * 32 + ww) : 0;   // in-bounds dummy
#pragma unroll
            for (int ci = 0; ci < 3; ++ci) {
                const float xv  = xn[ci * 1024 + ad];
                const float val = ok ? xv : 0.0f;      // pad -> e^0 = 1
                const float Ev  = fminf(__expf(val * INV_D), 3.0e38f);

                const int   k  = ci * 9 + ki * 3 + kj;
                const float4 t4 = thv4[k * 4 + wv];    // wave-uniform b128

                {
                    const float E  = Ev * t4.x;
                    const float l1 = __log2f(1.0f + E);
                    const float l2 = __log2f(fmaf(E, C_NEG, 1.0f));
                    acc0 = fmaf(l1, l1, acc0);
                    acc0 = fmaf(-l2, l2, acc0);
                }
                {
                    const float E  = Ev * t4.y;
                    const float l1 = __log2f(1.0f + E);
                    const float l2 = __log2f(fmaf(E, C_NEG, 1.0f));
                    acc1 = fmaf(l1, l1, acc1);
                    acc1 = fmaf(-l2, l2, acc1);
                }
                {
                    const float E  = Ev * t4.z;
                    const float l1 = __log2f(1.0f + E);
                    const float l2 = __log2f(fmaf(E, C_NEG, 1.0f));
                    acc2 = fmaf(l1, l1, acc2);
                    acc2 = fmaf(-l2, l2, acc2);
                }
                {
                    const float E  = Ev * t4.w;
                    const float l1 = __log2f(1.0f + E);
                    const float l2 = __log2f(fmaf(E, C_NEG, 1.0f));
                    acc3 = fmaf(l1, l1, acc3);
                    acc3 = fmaf(-l2, l2, acc3);
                }
            }
        }
    }

    const float acc[4] = {acc0, acc1, acc2, acc3};
#pragma unroll
    for (int i = 0; i < 4; ++i) {
        const int   c  = cbase + wv * 4 + i;
        const float vo = acc[i];                 // raw (unscaled) accumulator
        vout[(n << 16) + (c << 10) + hw] = vo;   // NCHW, coalesced per wave

        float s = vo, q = vo * vo;
#pragma unroll
        for (int off = 32; off > 0; off >>= 1) {
            s += __shfl_xor(s, off, 64);
            q += __shfl_xor(q, off, 64);
        }
        if (lane == 0) {
            psum[c * NCHUNK + chunk] = s;    // [channel][chunk] layout
            psq [c * NCHUNK + chunk] = q;
        }
    }
}

// ---------------------------------------------------------------------------
// Kernel 2: fused stats + BN apply (r5 version). Grid: 512 blocks = 64
// channels x 8 segments; each block redundantly reduces its channel's 512
// partials (deterministic double tree, L2-resident), then normalizes 4 full
// (n,c) planes in-place. Payload loads issued before the reduction.
// ---------------------------------------------------------------------------
__global__ __launch_bounds__(256)
void nlc_finish(const float* __restrict__ psum, const float* __restrict__ psq,
                const float* __restrict__ gamma, const float* __restrict__ beta,
                float* __restrict__ vout)
{
    const int b   = blockIdx.x;
    const int c   = b >> 3;        // channel
    const int seg = b & 7;         // 4-plane segment within the channel
    const int tid = threadIdx.x;

    // issue payload loads early (independent of the stats)
    float4* p0 = reinterpret_cast<float4*>(vout)
               + ((seg * 4 + 0) * 64 + c) * 256 + tid;
    float4* p1 = p0 + 64 * 256;
    float4* p2 = p1 + 64 * 256;
    float4* p3 = p2 + 64 * 256;
    float4 v0 = *p0, v1 = *p1, v2 = *p2, v3 = *p3;

    // block-redundant reduction of channel c's 512 partials (L2-resident)
    double s = (double)psum[c * NCHUNK + tid] + (double)psum[c * NCHUNK + 256 + tid];
    double q = (double)psq [c * NCHUNK + tid] + (double)psq [c * NCHUNK + 256 + tid];
#pragma unroll
    for (int off = 32; off > 0; off >>= 1) {
        s += __shfl_xor(s, off, 64);
        q += __shfl_xor(q, off, 64);
    }
    __shared__ double ls[4], lq[4];
    __shared__ float  scsh[2];
    if ((tid & 63) == 0) { ls[tid >> 6] = s; lq[tid >> 6] = q; }
    __syncthreads();
    if (tid == 0) {
        s = ls[0] + ls[1] + ls[2] + ls[3];
        q = lq[0] + lq[1] + lq[2] + lq[3];
        const double inv    = 1.0 / 32768.0;
        const double mean_a = s * inv;                       // acc units
        const double var_a  = q * inv - mean_a * mean_a;     // biased
        const double var_V  = var_a * OUT_SC * OUT_SC;
        const double rstd   = 1.0 / sqrt(var_V + 1e-5);
        const double sc     = (double)gamma[c] * rstd * OUT_SC;  // per acc
        const double sh     = (double)beta[c] - mean_a * sc;
        scsh[0] = (float)sc;
        scsh[1] = (float)sh;
    }
    __syncthreads();
    const float sc = scsh[0];
    const float sh = scsh[1];

#define NLC_BN4(v) \
    v.x = fmaf(v.x, sc, sh); v.y = fmaf(v.y, sc, sh); \
    v.z = fmaf(v.z, sc, sh); v.w = fmaf(v.w, sc, sh);
    NLC_BN4(v0) NLC_BN4(v1) NLC_BN4(v2) NLC_BN4(v3)
#undef NLC_BN4

    *p0 = v0; *p1 = v1; *p2 = v2; *p3 = v3;
}

extern "C" void kernel_launch(void* const* d_in, const int* in_sizes, int n_in,
                              void* d_out, int out_size, void* d_ws, size_t ws_size,
                              hipStream_t stream)
{
    const float* x     = (const float*)d_in[0];
    const float* theta = (const float*)d_in[1];
    const float* gamma = (const float*)d_in[2];
    const float* beta  = (const float*)d_in[3];
    float* out = (float*)d_out;

    float* psum = (float*)d_ws;                 // 64*512 floats
    float* psq  = psum + 64 * NCHUNK;           // 64*512 floats

    nlc_compute<<<NCHUNK * 4, 256, 0, stream>>>(x, theta, out, psum, psq);
    nlc_finish <<<512, 256, 0, stream>>>(psum, psq, gamma, beta, out);
}

// Round 8
// 33.793 us; speedup vs baseline: 3.5141x; 3.5141x over previous
//
#include <hip/hip_runtime.h>

// NonLinearConv2d: unfold(3x3,pad1) -> sum_k f((v_k - theta_kc)/D) with
// f(a) = softplus(a)^2 - softplus(a-DLT)^2, then BatchNorm2d (training,
// biased stats) per channel.
//
// Round 8: r4 math exactly (factored exponential, 2 v_log + 5 VALU/term,
// ci-major accumulation order) but Ev chunked per-ci into Ev[9] with
// '#pragma unroll 1' on the ci loop -> natural VGPR ~55 -> ~8 waves/SIMD
// WITHOUT any min-waves bound (round 7 showed coercion causes spill
// catastrophe: VGPR=32, 470MB scratch traffic). Border addr/mask precomputed
// once (10 regs). Finish = r5's 512-block fused stats+apply.

constexpr float INV_D  = 13.333333333333334f;   // 1/(2*n*VT) = 1/0.075
constexpr float C_NEG  = 0.2635971381157267f;   // e^-(V_D/DENOM) = e^-4/3
// V = acc * OUT_SC;  OUT_SC = ALPHA * R_TIA * ln(2)^2
constexpr double OUT_SC = 5.625e-5 * 0.48045301391820142;
constexpr int   NCHUNK = 512;                   // 32768 pixels / 64

// ---------------------------------------------------------------------------
// Kernel 1: raw acc (into d_out) + per-(channel,chunk) partial sum / sumsq.
// Grid: 2048 = 512 pixel-chunks x 4 channel-groups; block 256 = 4 waves;
// wave handles 64 consecutive pixels x 4 channels.
// ---------------------------------------------------------------------------
__global__ __launch_bounds__(256)
void nlc_compute(const float* __restrict__ x, const float* __restrict__ theta,
                 float* __restrict__ vout, float* __restrict__ psum,
                 float* __restrict__ psq)
{
    __shared__ alignas(16) float thc[27 * 16];  // e^{-theta*INV_D}, 16 ch
    const int tid   = threadIdx.x;
    const int chunk = blockIdx.x >> 2;
    const int cbase = (blockIdx.x & 3) * 16;

    for (int i = tid; i < 27 * 16; i += 256) {
        const int k = i >> 4, cc = i & 15;
        thc[i] = __expf(-theta[k * 64 + cbase + cc] * INV_D);
    }
    __syncthreads();

    const int lane = tid & 63;
    const int wv   = tid >> 6;
    const int p    = chunk * 64 + lane;   // global pixel id
    const int n    = p >> 10;
    const int hw   = p & 1023;
    const int h    = hw >> 5;
    const int w    = hw & 31;

    const float* xn = x + n * 3072;
    const float4* thv4 = reinterpret_cast<const float4*>(thc);

    // 9 border-masked offsets, computed once (ad: 9 regs, okm: 1 reg)
    int ad[9];
    unsigned okm = 0;
#pragma unroll
    for (int ki = 0; ki < 3; ++ki) {
#pragma unroll
        for (int kj = 0; kj < 3; ++kj) {
            const int  hh = h + ki - 1;
            const int  ww = w + kj - 1;
            const bool ok = ((unsigned)hh < 32u) & ((unsigned)ww < 32u);
            ad[ki * 3 + kj] = ok ? (hh * 32 + ww) : 0;
            okm |= (unsigned)ok << (ki * 3 + kj);
        }
    }

    float acc0 = 0.f, acc1 = 0.f, acc2 = 0.f, acc3 = 0.f;

#pragma unroll 1   // keep Ev live range at 9 regs: do NOT re-hoist to Ev[27]
    for (int ci = 0; ci < 3; ++ci) {
        float Ev[9];
#pragma unroll
        for (int j = 0; j < 9; ++j) {
            const float xv  = xn[ci * 1024 + ad[j]];   // L1/L2-resident
            const float val = ((okm >> j) & 1u) ? xv : 0.0f;  // pad -> e^0
            Ev[j] = fminf(__expf(val * INV_D), 3.0e38f);
        }
#pragma unroll
        for (int j = 0; j < 9; ++j) {
            const float4 t4 = thv4[(ci * 9 + j) * 4 + wv];  // wave-uniform
            {
                const float E  = Ev[j] * t4.x;
                const float l1 = __log2f(1.0f + E);
                const float l2 = __log2f(fmaf(E, C_NEG, 1.0f));
                acc0 = fmaf(l1, l1, acc0);
                acc0 = fmaf(-l2, l2, acc0);
            }
            {
                const float E  = Ev[j] * t4.y;
                const float l1 = __log2f(1.0f + E);
                const float l2 = __log2f(fmaf(E, C_NEG, 1.0f));
                acc1 = fmaf(l1, l1, acc1);
                acc1 = fmaf(-l2, l2, acc1);
            }
            {
                const float E  = Ev[j] * t4.z;
                const float l1 = __log2f(1.0f + E);
                const float l2 = __log2f(fmaf(E, C_NEG, 1.0f));
                acc2 = fmaf(l1, l1, acc2);
                acc2 = fmaf(-l2, l2, acc2);
            }
            {
                const float E  = Ev[j] * t4.w;
                const float l1 = __log2f(1.0f + E);
                const float l2 = __log2f(fmaf(E, C_NEG, 1.0f));
                acc3 = fmaf(l1, l1, acc3);
                acc3 = fmaf(-l2, l2, acc3);
            }
        }
    }

    const float acc[4] = {acc0, acc1, acc2, acc3};
#pragma unroll
    for (int i = 0; i < 4; ++i) {
        const int   c  = cbase + wv * 4 + i;
        const float vo = acc[i];                 // raw (unscaled) accumulator
        vout[(n << 16) + (c << 10) + hw] = vo;   // NCHW, coalesced per wave

        float s = vo, q = vo * vo;
#pragma unroll
        for (int off = 32; off > 0; off >>= 1) {
            s += __shfl_xor(s, off, 64);
            q += __shfl_xor(q, off, 64);
        }
        if (lane == 0) {
            psum[c * NCHUNK + chunk] = s;    // [channel][chunk] layout
            psq [c * NCHUNK + chunk] = q;
        }
    }
}

// ---------------------------------------------------------------------------
// Kernel 2: fused stats + BN apply (r5 version). Grid: 512 blocks = 64
// channels x 8 segments; each block redundantly reduces its channel's 512
// partials (deterministic double tree, L2-resident), then normalizes 4 full
// (n,c) planes in-place. Payload loads issued before the reduction.
// ---------------------------------------------------------------------------
__global__ __launch_bounds__(256)
void nlc_finish(const float* __restrict__ psum, const float* __restrict__ psq,
                const float* __restrict__ gamma, const float* __restrict__ beta,
                float* __restrict__ vout)
{
    const int b   = blockIdx.x;
    const int c   = b >> 3;        // channel
    const int seg = b & 7;         // 4-plane segment within the channel
    const int tid = threadIdx.x;

    // issue payload loads early (independent of the stats)
    float4* p0 = reinterpret_cast<float4*>(vout)
               + ((seg * 4 + 0) * 64 + c) * 256 + tid;
    float4* p1 = p0 + 64 * 256;
    float4* p2 = p1 + 64 * 256;
    float4* p3 = p2 + 64 * 256;
    float4 v0 = *p0, v1 = *p1, v2 = *p2, v3 = *p3;

    // block-redundant reduction of channel c's 512 partials (L2-resident)
    double s = (double)psum[c * NCHUNK + tid] + (double)psum[c * NCHUNK + 256 + tid];
    double q = (double)psq [c * NCHUNK + tid] + (double)psq [c * NCHUNK + 256 + tid];
#pragma unroll
    for (int off = 32; off > 0; off >>= 1) {
        s += __shfl_xor(s, off, 64);
        q += __shfl_xor(q, off, 64);
    }
    __shared__ double ls[4], lq[4];
    __shared__ float  scsh[2];
    if ((tid & 63) == 0) { ls[tid >> 6] = s; lq[tid >> 6] = q; }
    __syncthreads();
    if (tid == 0) {
        s = ls[0] + ls[1] + ls[2] + ls[3];
        q = lq[0] + lq[1] + lq[2] + lq[3];
        const double inv    = 1.0 / 32768.0;
        const double mean_a = s * inv;                       // acc units
        const double var_a  = q * inv - mean_a * mean_a;     // biased
        const double var_V  = var_a * OUT_SC * OUT_SC;
        const double rstd   = 1.0 / sqrt(var_V + 1e-5);
        const double sc     = (double)gamma[c] * rstd * OUT_SC;  // per acc
        const double sh     = (double)beta[c] - mean_a * sc;
        scsh[0] = (float)sc;
        scsh[1] = (float)sh;
    }
    __syncthreads();
    const float sc = scsh[0];
    const float sh = scsh[1];

#define NLC_BN4(v) \
    v.x = fmaf(v.x, sc, sh); v.y = fmaf(v.y, sc, sh); \
    v.z = fmaf(v.z, sc, sh); v.w = fmaf(v.w, sc, sh);
    NLC_BN4(v0) NLC_BN4(v1) NLC_BN4(v2) NLC_BN4(v3)
#undef NLC_BN4

    *p0 = v0; *p1 = v1; *p2 = v2; *p3 = v3;
}

extern "C" void kernel_launch(void* const* d_in, const int* in_sizes, int n_in,
                              void* d_out, int out_size, void* d_ws, size_t ws_size,
                              hipStream_t stream)
{
    const float* x     = (const float*)d_in[0];
    const float* theta = (const float*)d_in[1];
    const float* gamma = (const float*)d_in[2];
    const float* beta  = (const float*)d_in[3];
    float* out = (float*)d_out;

    float* psum = (float*)d_ws;                 // 64*512 floats
    float* psq  = psum + 64 * NCHUNK;           // 64*512 floats

    nlc_compute<<<NCHUNK * 4, 256, 0, stream>>>(x, theta, out, psum, psq);
    nlc_finish <<<512, 256, 0, stream>>>(psum, psq, gamma, beta, out);
}

// Round 9
// 33.628 us; speedup vs baseline: 3.5313x; 1.0049x over previous
//
#include <hip/hip_runtime.h>

// NonLinearConv2d: unfold(3x3,pad1) -> sum_k f((v_k - theta_kc)/D) with
// f(a) = softplus(a)^2 - softplus(a-DLT)^2, then BatchNorm2d (training,
// biased stats) per channel.
//
// Round 9: (a) wave-uniform Taylor skip. For E = e^{(v-th)/D} <= 0.125 on all
// 64 lanes (P~0.66 per (k,c): theta~U[0,9] vs v~N(0,1)), use
// f ~ E^2(TA - TB*E) (err <= 2.2e-4/term) instead of 2 v_log (~26 -> ~6 cyc).
// Branch is wave-uniform; exact 2-log body is the fall-through; occupancy at
// natural VGPR (~8 waves/SIMD, r8) hides branch stalls. (b) e^{x*INV_D}
// precomputed once in a tiny kernel (384 KB in d_ws) -- r8 recomputed each of
// 98K exps 144x (27/thread). Finish = r5/r8's 512-block fused stats+apply.

constexpr float INV_D  = 13.333333333333334f;   // 1/(2*n*VT) = 1/0.075
constexpr double CD    = 0.26359713811572677;   // e^-(V_D/DENOM) = e^-4/3
constexpr float C_NEG  = (float)CD;
constexpr double LN2SQ = 0.4804530139182014;
// V = acc * OUT_SC;  OUT_SC = ALPHA * R_TIA * ln(2)^2
constexpr double OUT_SC = 5.625e-5 * LN2SQ;
// Taylor (log2^2 units): f/ln2^2 ~ E^2 * (TA - TB*E)
constexpr float TA = (float)((1.0 - CD * CD) / LN2SQ);        // 1.9367483
constexpr float TB = (float)((1.0 - CD * CD * CD) / LN2SQ);   // 2.0432474
constexpr float E_THR = 0.125f;
constexpr int   NCHUNK = 512;                   // 32768 pixels / 64

// ---------------------------------------------------------------------------
// Kernel 0: precompute xe[i] = min(e^{x[i]*INV_D}, 3e38) (float4-vectorized).
// 98304 elements = 24576 float4 -> 96 blocks x 256.
// ---------------------------------------------------------------------------
__global__ __launch_bounds__(256)
void nlc_exp(const float* __restrict__ x, float* __restrict__ xe)
{
    const int i = blockIdx.x * 256 + threadIdx.x;
    float4 v = reinterpret_cast<const float4*>(x)[i];
    v.x = fminf(__expf(v.x * INV_D), 3.0e38f);
    v.y = fminf(__expf(v.y * INV_D), 3.0e38f);
    v.z = fminf(__expf(v.z * INV_D), 3.0e38f);
    v.w = fminf(__expf(v.w * INV_D), 3.0e38f);
    reinterpret_cast<float4*>(xe)[i] = v;
}

// ---------------------------------------------------------------------------
// Kernel 1: raw acc (into d_out) + per-(channel,chunk) partial sum / sumsq.
// Grid: 2048 = 512 pixel-chunks x 4 channel-groups; block 256 = 4 waves;
// wave handles 64 consecutive pixels x 4 channels.
// ---------------------------------------------------------------------------
__global__ __launch_bounds__(256)
void nlc_compute(const float* __restrict__ xe, const float* __restrict__ theta,
                 float* __restrict__ vout, float* __restrict__ psum,
                 float* __restrict__ psq)
{
    __shared__ alignas(16) float thc[27 * 16];  // e^{-theta*INV_D}, 16 ch
    const int tid   = threadIdx.x;
    const int chunk = blockIdx.x >> 2;
    const int cbase = (blockIdx.x & 3) * 16;

    for (int i = tid; i < 27 * 16; i += 256) {
        const int k = i >> 4, cc = i & 15;
        thc[i] = __expf(-theta[k * 64 + cbase + cc] * INV_D);
    }
    __syncthreads();

    const int lane = tid & 63;
    const int wv   = tid >> 6;
    const int p    = chunk * 64 + lane;   // global pixel id
    const int n    = p >> 10;
    const int hw   = p & 1023;
    const int h    = hw >> 5;
    const int w    = hw & 31;

    const float* xn = xe + n * 3072;
    const float4* thv4 = reinterpret_cast<const float4*>(thc);

    // 9 border-masked offsets, computed once
    int ad[9];
    unsigned okm = 0;
#pragma unroll
    for (int ki = 0; ki < 3; ++ki) {
#pragma unroll
        for (int kj = 0; kj < 3; ++kj) {
            const int  hh = h + ki - 1;
            const int  ww = w + kj - 1;
            const bool ok = ((unsigned)hh < 32u) & ((unsigned)ww < 32u);
            ad[ki * 3 + kj] = ok ? (hh * 32 + ww) : 0;
            okm |= (unsigned)ok << (ki * 3 + kj);
        }
    }

    float acc0 = 0.f, acc1 = 0.f, acc2 = 0.f, acc3 = 0.f;

#pragma unroll 1   // keep Ev live range at 9 regs (r8: prevents Ev[27] hoist)
    for (int ci = 0; ci < 3; ++ci) {
        float Ev[9];
#pragma unroll
        for (int j = 0; j < 9; ++j) {
            const float ev = xn[ci * 1024 + ad[j]];     // L1/L2-resident
            Ev[j] = ((okm >> j) & 1u) ? ev : 1.0f;      // pad -> e^0 = 1
        }
#pragma unroll
        for (int j = 0; j < 9; ++j) {
            const float4 t4 = thv4[(ci * 9 + j) * 4 + wv];  // wave-uniform
            const float E0 = Ev[j] * t4.x;
            const float E1 = Ev[j] * t4.y;
            const float E2 = Ev[j] * t4.z;
            const float E3 = Ev[j] * t4.w;

            if (__all(E0 <= E_THR)) {
                acc0 = fmaf(E0 * E0, fmaf(-TB, E0, TA), acc0);
            } else {
                const float l1 = __log2f(1.0f + E0);
                const float l2 = __log2f(fmaf(E0, C_NEG, 1.0f));
                acc0 = fmaf(l1, l1, acc0);
                acc0 = fmaf(-l2, l2, acc0);
            }
            if (__all(E1 <= E_THR)) {
                acc1 = fmaf(E1 * E1, fmaf(-TB, E1, TA), acc1);
            } else {
                const float l1 = __log2f(1.0f + E1);
                const float l2 = __log2f(fmaf(E1, C_NEG, 1.0f));
                acc1 = fmaf(l1, l1, acc1);
                acc1 = fmaf(-l2, l2, acc1);
            }
            if (__all(E2 <= E_THR)) {
                acc2 = fmaf(E2 * E2, fmaf(-TB, E2, TA), acc2);
            } else {
                const float l1 = __log2f(1.0f + E2);
                const float l2 = __log2f(fmaf(E2, C_NEG, 1.0f));
                acc2 = fmaf(l1, l1, acc2);
                acc2 = fmaf(-l2, l2, acc2);
            }
            if (__all(E3 <= E_THR)) {
                acc3 = fmaf(E3 * E3, fmaf(-TB, E3, TA), acc3);
            } else {
                const float l1 = __log2f(1.0f + E3);
                const float l2 = __log2f(fmaf(E3, C_NEG, 1.0f));
                acc3 = fmaf(l1, l1, acc3);
                acc3 = fmaf(-l2, l2, acc3);
            }
        }
    }

    const float acc[4] = {acc0, acc1, acc2, acc3};
#pragma unroll
    for (int i = 0; i < 4; ++i) {
        const int   c  = cbase + wv * 4 + i;
        const float vo = acc[i];                 // raw (unscaled) accumulator
        vout[(n << 16) + (c << 10) + hw] = vo;   // NCHW, coalesced per wave

        float s = vo, q = vo * vo;
#pragma unroll
        for (int off = 32; off > 0; off >>= 1) {
            s += __shfl_xor(s, off, 64);
            q += __shfl_xor(q, off, 64);
        }
        if (lane == 0) {
            psum[c * NCHUNK + chunk] = s;    // [channel][chunk] layout
            psq [c * NCHUNK + chunk] = q;
        }
    }
}

// ---------------------------------------------------------------------------
// Kernel 2: fused stats + BN apply. Grid: 512 blocks = 64 channels x 8
// segments; each block redundantly reduces its channel's 512 partials
// (deterministic double tree, L2-resident), then normalizes 4 full (n,c)
// planes in-place. Payload loads issued before the reduction.
// ---------------------------------------------------------------------------
__global__ __launch_bounds__(256)
void nlc_finish(const float* __restrict__ psum, const float* __restrict__ psq,
                const float* __restrict__ gamma, const float* __restrict__ beta,
                float* __restrict__ vout)
{
    const int b   = blockIdx.x;
    const int c   = b >> 3;        // channel
    const int seg = b & 7;         // 4-plane segment within the channel
    const int tid = threadIdx.x;

    // issue payload loads early (independent of the stats)
    float4* p0 = reinterpret_cast<float4*>(vout)
               + ((seg * 4 + 0) * 64 + c) * 256 + tid;
    float4* p1 = p0 + 64 * 256;
    float4* p2 = p1 + 64 * 256;
    float4* p3 = p2 + 64 * 256;
    float4 v0 = *p0, v1 = *p1, v2 = *p2, v3 = *p3;

    // block-redundant reduction of channel c's 512 partials (L2-resident)
    double s = (double)psum[c * NCHUNK + tid] + (double)psum[c * NCHUNK + 256 + tid];
    double q = (double)psq [c * NCHUNK + tid] + (double)psq [c * NCHUNK + 256 + tid];
#pragma unroll
    for (int off = 32; off > 0; off >>= 1) {
        s += __shfl_xor(s, off, 64);
        q += __shfl_xor(q, off, 64);
    }
    __shared__ double ls[4], lq[4];
    __shared__ float  scsh[2];
    if ((tid & 63) == 0) { ls[tid >> 6] = s; lq[tid >> 6] = q; }
    __syncthreads();
    if (tid == 0) {
        s = ls[0] + ls[1] + ls[2] + ls[3];
        q = lq[0] + lq[1] + lq[2] + lq[3];
        const double inv    = 1.0 / 32768.0;
        const double mean_a = s * inv;                       // acc units
        const double var_a  = q * inv - mean_a * mean_a;     // biased
        const double var_V  = var_a * OUT_SC * OUT_SC;
        const double rstd   = 1.0 / sqrt(var_V + 1e-5);
        const double sc     = (double)gamma[c] * rstd * OUT_SC;  // per acc
        const double sh     = (double)beta[c] - mean_a * sc;
        scsh[0] = (float)sc;
        scsh[1] = (float)sh;
    }
    __syncthreads();
    const float sc = scsh[0];
    const float sh = scsh[1];

#define NLC_BN4(v) \
    v.x = fmaf(v.x, sc, sh); v.y = fmaf(v.y, sc, sh); \
    v.z = fmaf(v.z, sc, sh); v.w = fmaf(v.w, sc, sh);
    NLC_BN4(v0) NLC_BN4(v1) NLC_BN4(v2) NLC_BN4(v3)
#undef NLC_BN4

    *p0 = v0; *p1 = v1; *p2 = v2; *p3 = v3;
}

extern "C" void kernel_launch(void* const* d_in, const int* in_sizes, int n_in,
                              void* d_out, int out_size, void* d_ws, size_t ws_size,
                              hipStream_t stream)
{
    const float* x     = (const float*)d_in[0];
    const float* theta = (const float*)d_in[1];
    const float* gamma = (const float*)d_in[2];
    const float* beta  = (const float*)d_in[3];
    float* out = (float*)d_out;

    float* psum = (float*)d_ws;                 // 64*512 floats
    float* psq  = psum + 64 * NCHUNK;           // 64*512 floats
    float* xe   = psq  + 64 * NCHUNK;           // 98304 floats (e^{x/D})

    nlc_exp    <<<96, 256, 0, stream>>>(x, xe);
    nlc_compute<<<NCHUNK * 4, 256, 0, stream>>>(xe, theta, out, psum, psq);
    nlc_finish <<<512, 256, 0, stream>>>(psum, psq, gamma, beta, out);
}

// Round 10
// 33.465 us; speedup vs baseline: 3.5485x; 1.0049x over previous
//
#include <hip/hip_runtime.h>

// NonLinearConv2d: unfold(3x3,pad1) -> sum_k f((v_k - theta_kc)/D) with
// f(a) = softplus(a)^2 - softplus(a-DLT)^2, then BatchNorm2d (training,
// biased stats) per channel.
//
// Round 10: r9 EXACTLY, plus `asm volatile("")` at the head of each slow
// (2-log) branch body. Hypothesis: r9's null was the compiler if-converting
// the __all() diamonds (computing logs always + cndmask). A volatile asm
// cannot be speculated -> forces a genuine s_cbranch, letting ~60% of terms
// actually skip both v_log ops. Numerics bit-identical to r9 (validated:
// absmax 0.0078125).

constexpr float INV_D  = 13.333333333333334f;   // 1/(2*n*VT) = 1/0.075
constexpr double CD    = 0.26359713811572677;   // e^-(V_D/DENOM) = e^-4/3
constexpr float C_NEG  = (float)CD;
constexpr double LN2SQ = 0.4804530139182014;
// V = acc * OUT_SC;  OUT_SC = ALPHA * R_TIA * ln(2)^2
constexpr double OUT_SC = 5.625e-5 * LN2SQ;
// Taylor (log2^2 units): f/ln2^2 ~ E^2 * (TA - TB*E)
constexpr float TA = (float)((1.0 - CD * CD) / LN2SQ);        // 1.9367483
constexpr float TB = (float)((1.0 - CD * CD * CD) / LN2SQ);   // 2.0432474
constexpr float E_THR = 0.125f;
constexpr int   NCHUNK = 512;                   // 32768 pixels / 64

// ---------------------------------------------------------------------------
// Kernel 0: precompute xe[i] = min(e^{x[i]*INV_D}, 3e38) (float4-vectorized).
// ---------------------------------------------------------------------------
__global__ __launch_bounds__(256)
void nlc_exp(const float* __restrict__ x, float* __restrict__ xe)
{
    const int i = blockIdx.x * 256 + threadIdx.x;
    float4 v = reinterpret_cast<const float4*>(x)[i];
    v.x = fminf(__expf(v.x * INV_D), 3.0e38f);
    v.y = fminf(__expf(v.y * INV_D), 3.0e38f);
    v.z = fminf(__expf(v.z * INV_D), 3.0e38f);
    v.w = fminf(__expf(v.w * INV_D), 3.0e38f);
    reinterpret_cast<float4*>(xe)[i] = v;
}

// ---------------------------------------------------------------------------
// Kernel 1: raw acc (into d_out) + per-(channel,chunk) partial sum / sumsq.
// Grid: 2048 = 512 pixel-chunks x 4 channel-groups; block 256 = 4 waves;
// wave handles 64 consecutive pixels x 4 channels.
// ---------------------------------------------------------------------------
__global__ __launch_bounds__(256)
void nlc_compute(const float* __restrict__ xe, const float* __restrict__ theta,
                 float* __restrict__ vout, float* __restrict__ psum,
                 float* __restrict__ psq)
{
    __shared__ alignas(16) float thc[27 * 16];  // e^{-theta*INV_D}, 16 ch
    const int tid   = threadIdx.x;
    const int chunk = blockIdx.x >> 2;
    const int cbase = (blockIdx.x & 3) * 16;

    for (int i = tid; i < 27 * 16; i += 256) {
        const int k = i >> 4, cc = i & 15;
        thc[i] = __expf(-theta[k * 64 + cbase + cc] * INV_D);
    }
    __syncthreads();

    const int lane = tid & 63;
    const int wv   = tid >> 6;
    const int p    = chunk * 64 + lane;   // global pixel id
    const int n    = p >> 10;
    const int hw   = p & 1023;
    const int h    = hw >> 5;
    const int w    = hw & 31;

    const float* xn = xe + n * 3072;
    const float4* thv4 = reinterpret_cast<const float4*>(thc);

    // 9 border-masked offsets, computed once
    int ad[9];
    unsigned okm = 0;
#pragma unroll
    for (int ki = 0; ki < 3; ++ki) {
#pragma unroll
        for (int kj = 0; kj < 3; ++kj) {
            const int  hh = h + ki - 1;
            const int  ww = w + kj - 1;
            const bool ok = ((unsigned)hh < 32u) & ((unsigned)ww < 32u);
            ad[ki * 3 + kj] = ok ? (hh * 32 + ww) : 0;
            okm |= (unsigned)ok << (ki * 3 + kj);
        }
    }

    float acc0 = 0.f, acc1 = 0.f, acc2 = 0.f, acc3 = 0.f;

#pragma unroll 1   // keep Ev live range at 9 regs (r8: prevents Ev[27] hoist)
    for (int ci = 0; ci < 3; ++ci) {
        float Ev[9];
#pragma unroll
        for (int j = 0; j < 9; ++j) {
            const float ev = xn[ci * 1024 + ad[j]];     // L1/L2-resident
            Ev[j] = ((okm >> j) & 1u) ? ev : 1.0f;      // pad -> e^0 = 1
        }
#pragma unroll
        for (int j = 0; j < 9; ++j) {
            const float4 t4 = thv4[(ci * 9 + j) * 4 + wv];  // wave-uniform
            const float E0 = Ev[j] * t4.x;
            const float E1 = Ev[j] * t4.y;
            const float E2 = Ev[j] * t4.z;
            const float E3 = Ev[j] * t4.w;

            if (__all(E0 <= E_THR)) {
                acc0 = fmaf(E0 * E0, fmaf(-TB, E0, TA), acc0);
            } else {
                asm volatile("");   // forbid if-conversion of this body
                const float l1 = __log2f(1.0f + E0);
                const float l2 = __log2f(fmaf(E0, C_NEG, 1.0f));
                acc0 = fmaf(l1, l1, acc0);
                acc0 = fmaf(-l2, l2, acc0);
            }
            if (__all(E1 <= E_THR)) {
                acc1 = fmaf(E1 * E1, fmaf(-TB, E1, TA), acc1);
            } else {
                asm volatile("");
                const float l1 = __log2f(1.0f + E1);
                const float l2 = __log2f(fmaf(E1, C_NEG, 1.0f));
                acc1 = fmaf(l1, l1, acc1);
                acc1 = fmaf(-l2, l2, acc1);
            }
            if (__all(E2 <= E_THR)) {
                acc2 = fmaf(E2 * E2, fmaf(-TB, E2, TA), acc2);
            } else {
                asm volatile("");
                const float l1 = __log2f(1.0f + E2);
                const float l2 = __log2f(fmaf(E2, C_NEG, 1.0f));
                acc2 = fmaf(l1, l1, acc2);
                acc2 = fmaf(-l2, l2, acc2);
            }
            if (__all(E3 <= E_THR)) {
                acc3 = fmaf(E3 * E3, fmaf(-TB, E3, TA), acc3);
            } else {
                asm volatile("");
                const float l1 = __log2f(1.0f + E3);
                const float l2 = __log2f(fmaf(E3, C_NEG, 1.0f));
                acc3 = fmaf(l1, l1, acc3);
                acc3 = fmaf(-l2, l2, acc3);
            }
        }
    }

    const float acc[4] = {acc0, acc1, acc2, acc3};
#pragma unroll
    for (int i = 0; i < 4; ++i) {
        const int   c  = cbase + wv * 4 + i;
        const float vo = acc[i];                 // raw (unscaled) accumulator
        vout[(n << 16) + (c << 10) + hw] = vo;   // NCHW, coalesced per wave

        float s = vo, q = vo * vo;
#pragma unroll
        for (int off = 32; off > 0; off >>= 1) {
            s += __shfl_xor(s, off, 64);
            q += __shfl_xor(q, off, 64);
        }
        if (lane == 0) {
            psum[c * NCHUNK + chunk] = s;    // [channel][chunk] layout
            psq [c * NCHUNK + chunk] = q;
        }
    }
}

// ---------------------------------------------------------------------------
// Kernel 2: fused stats + BN apply. Grid: 512 blocks = 64 channels x 8
// segments; each block redundantly reduces its channel's 512 partials
// (deterministic double tree, L2-resident), then normalizes 4 full (n,c)
// planes in-place. Payload loads issued before the reduction.
// ---------------------------------------------------------------------------
__global__ __launch_bounds__(256)
void nlc_finish(const float* __restrict__ psum, const float* __restrict__ psq,
                const float* __restrict__ gamma, const float* __restrict__ beta,
                float* __restrict__ vout)
{
    const int b   = blockIdx.x;
    const int c   = b >> 3;        // channel
    const int seg = b & 7;         // 4-plane segment within the channel
    const int tid = threadIdx.x;

    // issue payload loads early (independent of the stats)
    float4* p0 = reinterpret_cast<float4*>(vout)
               + ((seg * 4 + 0) * 64 + c) * 256 + tid;
    float4* p1 = p0 + 64 * 256;
    float4* p2 = p1 + 64 * 256;
    float4* p3 = p2 + 64 * 256;
    float4 v0 = *p0, v1 = *p1, v2 = *p2, v3 = *p3;

    // block-redundant reduction of channel c's 512 partials (L2-resident)
    double s = (double)psum[c * NCHUNK + tid] + (double)psum[c * NCHUNK + 256 + tid];
    double q = (double)psq [c * NCHUNK + tid] + (double)psq [c * NCHUNK + 256 + tid];
#pragma unroll
    for (int off = 32; off > 0; off >>= 1) {
        s += __shfl_xor(s, off, 64);
        q += __shfl_xor(q, off, 64);
    }
    __shared__ double ls[4], lq[4];
    __shared__ float  scsh[2];
    if ((tid & 63) == 0) { ls[tid >> 6] = s; lq[tid >> 6] = q; }
    __syncthreads();
    if (tid == 0) {
        s = ls[0] + ls[1] + ls[2] + ls[3];
        q = lq[0] + lq[1] + lq[2] + lq[3];
        const double inv    = 1.0 / 32768.0;
        const double mean_a = s * inv;                       // acc units
        const double var_a  = q * inv - mean_a * mean_a;     // biased
        const double var_V  = var_a * OUT_SC * OUT_SC;
        const double rstd   = 1.0 / sqrt(var_V + 1e-5);
        const double sc     = (double)gamma[c] * rstd * OUT_SC;  // per acc
        const double sh     = (double)beta[c] - mean_a * sc;
        scsh[0] = (float)sc;
        scsh[1] = (float)sh;
    }
    __syncthreads();
    const float sc = scsh[0];
    const float sh = scsh[1];

#define NLC_BN4(v) \
    v.x = fmaf(v.x, sc, sh); v.y = fmaf(v.y, sc, sh); \
    v.z = fmaf(v.z, sc, sh); v.w = fmaf(v.w, sc, sh);
    NLC_BN4(v0) NLC_BN4(v1) NLC_BN4(v2) NLC_BN4(v3)
#undef NLC_BN4

    *p0 = v0; *p1 = v1; *p2 = v2; *p3 = v3;
}

extern "C" void kernel_launch(void* const* d_in, const int* in_sizes, int n_in,
                              void* d_out, int out_size, void* d_ws, size_t ws_size,
                              hipStream_t stream)
{
    const float* x     = (const float*)d_in[0];
    const float* theta = (const float*)d_in[1];
    const float* gamma = (const float*)d_in[2];
    const float* beta  = (const float*)d_in[3];
    float* out = (float*)d_out;

    float* psum = (float*)d_ws;                 // 64*512 floats
    float* psq  = psum + 64 * NCHUNK;           // 64*512 floats
    float* xe   = psq  + 64 * NCHUNK;           // 98304 floats (e^{x/D})

    nlc_exp    <<<96, 256, 0, stream>>>(x, xe);
    nlc_compute<<<NCHUNK * 4, 256, 0, stream>>>(xe, theta, out, psum, psq);
    nlc_finish <<<512, 256, 0, stream>>>(psum, psq, gamma, beta, out);
}